// Round 13
// baseline (423.974 us; speedup 1.0000x reference)
//
#include <hip/hip_runtime.h>

#define NN 200000
#define NE 1000000
#define DD 64
#define NCHUNK 196   // ceil(NN / 1024)

typedef __bf16 bf16x4 __attribute__((ext_vector_type(4)));
typedef __bf16 bf16x8 __attribute__((ext_vector_type(8)));
typedef float  f32x4  __attribute__((ext_vector_type(4)));
typedef int    i32x4  __attribute__((ext_vector_type(4)));

static __device__ __forceinline__ bf16x8 pack8(const float* __restrict__ p) {
    float4 a = *reinterpret_cast<const float4*>(p);
    float4 b = *reinterpret_cast<const float4*>(p + 4);
    bf16x8 r;
    r[0] = (__bf16)a.x; r[1] = (__bf16)a.y; r[2] = (__bf16)a.z; r[3] = (__bf16)a.w;
    r[4] = (__bf16)b.x; r[5] = (__bf16)b.y; r[6] = (__bf16)b.z; r[7] = (__bf16)b.w;
    return r;
}

// ---------- counts zero ----------
__global__ __launch_bounds__(256) void k_zero(int* __restrict__ counts) {
    const int i = (blockIdx.x * 256 + threadIdx.x) * 4;
    if (i + 3 < NN) *reinterpret_cast<int4*>(counts + i) = make_int4(0, 0, 0, 0);
    else for (int j = i; j < NN; ++j) counts[j] = 0;
}

// ---------- Prep: histogram (blocks 0..1023) || interleaved ci-folded table ----------
// ftc[s][t*8+0..3] = bf16(f2[s][t*4..]*ci[s]); ftc[s][t*8+4..7] = bf16(f3[..]*ci[s])
__global__ __launch_bounds__(256) void k_prep(
    const int* __restrict__ dst, const float* __restrict__ f2,
    const float* __restrict__ f3, const float* __restrict__ ci,
    int* __restrict__ counts, __bf16* __restrict__ ftc)
{
    const int b = blockIdx.x;
    if (b < 1024) {
        for (int e = b * 256 + threadIdx.x; e < NE; e += 1024 * 256)
            atomicAdd(&counts[dst[e]], 1);
    } else {
        const int nconv = (gridDim.x - 1024) * 256;
        const int total = NN * 16;                    // 16B output chunks
        for (int cch = (b - 1024) * 256 + threadIdx.x; cch < total; cch += nconv) {
            const int row = cch >> 4;
            const int t   = cch & 15;
            const float c = ci[row];
            const float4 a = *reinterpret_cast<const float4*>(f2 + (size_t)row * DD + t * 4);
            const float4 v = *reinterpret_cast<const float4*>(f3 + (size_t)row * DD + t * 4);
            bf16x8 o;
            o[0] = (__bf16)(a.x * c); o[1] = (__bf16)(a.y * c);
            o[2] = (__bf16)(a.z * c); o[3] = (__bf16)(a.w * c);
            o[4] = (__bf16)(v.x * c); o[5] = (__bf16)(v.y * c);
            o[6] = (__bf16)(v.z * c); o[7] = (__bf16)(v.w * c);
            *reinterpret_cast<bf16x8*>(ftc + (size_t)row * 128 + t * 8) = o;
        }
    }
}

// ---------- CSR scan ----------
__global__ __launch_bounds__(256) void k_chunk_sums(const int* __restrict__ counts,
                                                    int* __restrict__ csum) {
    const int b = blockIdx.x, tid = threadIdx.x;
    const int base = b * 1024 + tid * 4;
    int s = 0;
#pragma unroll
    for (int j = 0; j < 4; ++j) {
        const int i = base + j;
        if (i < NN) s += counts[i];
    }
#pragma unroll
    for (int d = 32; d > 0; d >>= 1) s += __shfl_down(s, d);
    __shared__ int wsum[4];
    if ((tid & 63) == 0) wsum[tid >> 6] = s;
    __syncthreads();
    if (tid == 0) csum[b] = wsum[0] + wsum[1] + wsum[2] + wsum[3];
}

__global__ void k_scan_chunks(const int* __restrict__ csum, int* __restrict__ cofs) {
    if (threadIdx.x == 0 && blockIdx.x == 0) {
        int acc = 0;
        for (int i = 0; i < NCHUNK; ++i) { cofs[i] = acc; acc += csum[i]; }
    }
}

__global__ __launch_bounds__(256) void k_chunk_scan(const int* __restrict__ counts,
                                                    const int* __restrict__ cofs,
                                                    int* __restrict__ offs,
                                                    int* __restrict__ cursor) {
    const int b = blockIdx.x, tid = threadIdx.x;
    const int lane = tid & 63, wv = tid >> 6;
    const int base = b * 1024 + tid * 4;
    int c[4];
#pragma unroll
    for (int j = 0; j < 4; ++j) {
        const int i = base + j;
        c[j] = (i < NN) ? counts[i] : 0;
    }
    const int ls = c[0] + c[1] + c[2] + c[3];
    int v = ls;
#pragma unroll
    for (int d = 1; d < 64; d <<= 1) {
        const int u = __shfl_up(v, d);
        if (lane >= d) v += u;
    }
    __shared__ int wsum[4];
    if (lane == 63) wsum[wv] = v;
    __syncthreads();
    int wbase = 0;
    for (int w = 0; w < wv; ++w) wbase += wsum[w];
    int excl = cofs[b] + wbase + (v - ls);
#pragma unroll
    for (int j = 0; j < 4; ++j) {
        const int i = base + j;
        if (i < NN) { offs[i] = excl; cursor[i] = excl; }
        excl += c[j];
    }
}

// Fill CSR slots: epack[pos] = {edge, src, bits(ci[src]), 0} — one 16B write.
__global__ __launch_bounds__(256) void k_permfill(const int* __restrict__ dst,
                                                  const int* __restrict__ src,
                                                  const float* __restrict__ ci,
                                                  int* __restrict__ cursor,
                                                  int4* __restrict__ epack) {
    for (int e = blockIdx.x * blockDim.x + threadIdx.x; e < NE;
         e += gridDim.x * blockDim.x) {
        const int s = src[e];
        const float cs = ci[s];
        const int pos = atomicAdd(&cursor[dst[e]], 1);
        epack[pos] = make_int4(e, s, __float_as_int(cs), 0);
    }
}

// ---------- Fused pull + node-GEMM ----------
// Block = 256 threads = 16 quarters = 16 nodes = one MFMA A-tile.
// Unroll-4: four independent accumulator chains per quarter (4 edges in flight).
// NT loads on single-use streams (review, epack) keep ftc L3-resident.
__global__ __launch_bounds__(256) void k_pull_fused(
    const int4* __restrict__ epack, const int* __restrict__ offs,
    const int* __restrict__ counts, const float* __restrict__ review,
    const float* __restrict__ ci, const __bf16* __restrict__ ftc,
    const float* __restrict__ W1, const float* __restrict__ W2,
    float* __restrict__ out_rst, float* __restrict__ out_re,
    float* __restrict__ out_id)
{
    __shared__ __bf16 At[16][72];   // bf16(cid*hx); padded row (144B) vs bank conflicts
    __shared__ float  S2[16][68];   // cid*sum(f2c); padded row (272B)

    const int tid = threadIdx.x;
    const int l16 = tid & 15;
    const int q   = tid >> 4;               // node-in-block
    const int n   = blockIdx.x * 16 + q;

    const int beg = offs[n];
    const int cnt = counts[n];

    f32x4 ax[4], a2[4], a3[4];
#pragma unroll
    for (int u = 0; u < 4; ++u) {
        ax[u] = (f32x4){0.f, 0.f, 0.f, 0.f};
        a2[u] = (f32x4){0.f, 0.f, 0.f, 0.f};
        a3[u] = (f32x4){0.f, 0.f, 0.f, 0.f};
    }

    int k = 0;
    for (; k + 4 <= cnt; k += 4) {
        i32x4 ep[4];
#pragma unroll
        for (int u = 0; u < 4; ++u)
            ep[u] = __builtin_nontemporal_load(
                reinterpret_cast<const i32x4*>(epack + (size_t)(beg + k + u)));
        f32x4 r[4];
        bf16x8 t[4];
#pragma unroll
        for (int u = 0; u < 4; ++u) {
            r[u] = __builtin_nontemporal_load(reinterpret_cast<const f32x4*>(
                review + (size_t)ep[u][0] * DD + l16 * 4));
            t[u] = *reinterpret_cast<const bf16x8*>(
                ftc + (size_t)ep[u][1] * 128 + l16 * 8);
        }
#pragma unroll
        for (int u = 0; u < 4; ++u) {
            const float cs = __int_as_float(ep[u][2]);
            ax[u][0] = fmaf(r[u][0], cs, ax[u][0]);
            ax[u][1] = fmaf(r[u][1], cs, ax[u][1]);
            ax[u][2] = fmaf(r[u][2], cs, ax[u][2]);
            ax[u][3] = fmaf(r[u][3], cs, ax[u][3]);
            a2[u][0] += (float)t[u][0]; a2[u][1] += (float)t[u][1];
            a2[u][2] += (float)t[u][2]; a2[u][3] += (float)t[u][3];
            a3[u][0] += (float)t[u][4]; a3[u][1] += (float)t[u][5];
            a3[u][2] += (float)t[u][6]; a3[u][3] += (float)t[u][7];
        }
    }
    for (; k < cnt; ++k) {
        const int u = k & 3;
        const i32x4 ep = __builtin_nontemporal_load(
            reinterpret_cast<const i32x4*>(epack + (size_t)(beg + k)));
        const f32x4 r = __builtin_nontemporal_load(reinterpret_cast<const f32x4*>(
            review + (size_t)ep[0] * DD + l16 * 4));
        const bf16x8 t = *reinterpret_cast<const bf16x8*>(
            ftc + (size_t)ep[1] * 128 + l16 * 8);
        const float cs = __int_as_float(ep[2]);
        ax[u][0] = fmaf(r[0], cs, ax[u][0]);
        ax[u][1] = fmaf(r[1], cs, ax[u][1]);
        ax[u][2] = fmaf(r[2], cs, ax[u][2]);
        ax[u][3] = fmaf(r[3], cs, ax[u][3]);
        a2[u][0] += (float)t[0]; a2[u][1] += (float)t[1];
        a2[u][2] += (float)t[2]; a2[u][3] += (float)t[3];
        a3[u][0] += (float)t[4]; a3[u][1] += (float)t[5];
        a3[u][2] += (float)t[6]; a3[u][3] += (float)t[7];
    }

    const float cid = ci[n];
    f32x4 axs = {ax[0][0]+ax[1][0]+ax[2][0]+ax[3][0], ax[0][1]+ax[1][1]+ax[2][1]+ax[3][1],
                 ax[0][2]+ax[1][2]+ax[2][2]+ax[3][2], ax[0][3]+ax[1][3]+ax[2][3]+ax[3][3]};
    f32x4 a2s = {a2[0][0]+a2[1][0]+a2[2][0]+a2[3][0], a2[0][1]+a2[1][1]+a2[2][1]+a2[3][1],
                 a2[0][2]+a2[1][2]+a2[2][2]+a2[3][2], a2[0][3]+a2[1][3]+a2[2][3]+a2[3][3]};
    f32x4 a3s = {a3[0][0]+a3[1][0]+a3[2][0]+a3[3][0], a3[0][1]+a3[1][1]+a3[2][1]+a3[3][1],
                 a3[0][2]+a3[1][2]+a3[2][2]+a3[3][2], a3[0][3]+a3[1][3]+a3[2][3]+a3[3][3]};

    // out_id final (streaming).
    f32x4 v3 = {a3s[0] * cid, a3s[1] * cid, a3s[2] * cid, a3s[3] * cid};
    __builtin_nontemporal_store(v3, reinterpret_cast<f32x4*>(out_id + (size_t)n * DD + l16 * 4));

    // Stage GEMM input tiles.
    bf16x4 hb;
    hb[0] = (__bf16)(axs[0] * cid); hb[1] = (__bf16)(axs[1] * cid);
    hb[2] = (__bf16)(axs[2] * cid); hb[3] = (__bf16)(axs[3] * cid);
    *reinterpret_cast<bf16x4*>(&At[q][l16 * 4]) = hb;
    f32x4 s2v = {a2s[0] * cid, a2s[1] * cid, a2s[2] * cid, a2s[3] * cid};
    *reinterpret_cast<f32x4*>(&S2[q][l16 * 4]) = s2v;
    __syncthreads();

    // GEMM: wave w computes col-block w for both W1 (out_re) and W2 (out_rst).
    const int w  = tid >> 6;          // 0..3
    const int lq = (tid & 63) >> 4;   // 0..3
    bf16x8 w1f[2], w2f[2];
#pragma unroll
    for (int kk = 0; kk < 2; ++kk) {
        const int off = (w * 16 + l16) * DD + kk * 32 + lq * 8;
        w1f[kk] = pack8(W1 + off);
        w2f[kk] = pack8(W2 + off);
    }
    const bf16x8 a0 = *reinterpret_cast<const bf16x8*>(&At[l16][lq * 8]);
    const bf16x8 a1 = *reinterpret_cast<const bf16x8*>(&At[l16][lq * 8 + 32]);

    const f32x4 zero = {0.f, 0.f, 0.f, 0.f};
    f32x4 acc1 = zero, acc2 = zero;
    acc1 = __builtin_amdgcn_mfma_f32_16x16x32_bf16(a0, w1f[0], acc1, 0, 0, 0);
    acc1 = __builtin_amdgcn_mfma_f32_16x16x32_bf16(a1, w1f[1], acc1, 0, 0, 0);
    acc2 = __builtin_amdgcn_mfma_f32_16x16x32_bf16(a0, w2f[0], acc2, 0, 0, 0);
    acc2 = __builtin_amdgcn_mfma_f32_16x16x32_bf16(a1, w2f[1], acc2, 0, 0, 0);

    const int base = blockIdx.x * 16;
#pragma unroll
    for (int i = 0; i < 4; ++i) {
        const int row = lq * 4 + i;
        const size_t o = (size_t)(base + row) * DD + w * 16 + l16;
        __builtin_nontemporal_store(acc1[i], out_re + o);
        __builtin_nontemporal_store(acc2[i] + S2[row][w * 16 + l16], out_rst + o);
    }
}

// ---------- Fallback (round-2 proven kernel) if ws too small ----------
__global__ __launch_bounds__(256) void gcn_mfma_kernel(
    const int* __restrict__ src, const int* __restrict__ dst,
    const float* __restrict__ review, const float* __restrict__ ci,
    const float* __restrict__ W1, const float* __restrict__ W2,
    const float* __restrict__ f2, const float* __restrict__ f3,
    float* __restrict__ out)
{
    float* out_rst = out;
    float* out_re  = out + (size_t)NN * DD;
    float* out_id  = out + 2 * (size_t)NN * DD;
    const int lane = threadIdx.x & 63;
    const int l16  = lane & 15;
    const int lq   = lane >> 4;
    const int wid  = blockIdx.x * (blockDim.x >> 6) + (threadIdx.x >> 6);
    const int nw   = gridDim.x * (blockDim.x >> 6);

    bf16x8 w1f[4][2], w2f[4][2];
#pragma unroll
    for (int c = 0; c < 4; ++c)
#pragma unroll
        for (int kk = 0; kk < 2; ++kk) {
            const int off = (c * 16 + l16) * DD + kk * 32 + lq * 8;
            w1f[c][kk] = pack8(W1 + off);
            w2f[c][kk] = pack8(W2 + off);
        }
    const f32x4 zero = {0.f, 0.f, 0.f, 0.f};
    for (int t = wid; t < NE / 16; t += nw) {
        const int e0 = t * 16;
        const float* xr = review + (size_t)(e0 + l16) * DD + lq * 8;
        const bf16x8 a0 = pack8(xr);
        const bf16x8 a1 = pack8(xr + 32);
        f32x4 acc1[4], acc2[4];
#pragma unroll
        for (int c = 0; c < 4; ++c) { acc1[c] = zero; acc2[c] = zero; }
#pragma unroll
        for (int c = 0; c < 4; ++c) {
            acc1[c] = __builtin_amdgcn_mfma_f32_16x16x32_bf16(a0, w1f[c][0], acc1[c], 0, 0, 0);
            acc1[c] = __builtin_amdgcn_mfma_f32_16x16x32_bf16(a1, w1f[c][1], acc1[c], 0, 0, 0);
            acc2[c] = __builtin_amdgcn_mfma_f32_16x16x32_bf16(a0, w2f[c][0], acc2[c], 0, 0, 0);
            acc2[c] = __builtin_amdgcn_mfma_f32_16x16x32_bf16(a1, w2f[c][1], acc2[c], 0, 0, 0);
        }
        int sA[4], dA[4]; float cf[4];
#pragma unroll
        for (int i = 0; i < 4; ++i) {
            const int e = e0 + lq * 4 + i;
            sA[i] = src[e]; dA[i] = dst[e];
            cf[i] = ci[sA[i]] * ci[dA[i]];
        }
#pragma unroll
        for (int i = 0; i < 4; ++i) {
            const size_t so = (size_t)sA[i] * DD;
            const size_t dofs = (size_t)dA[i] * DD;
            const float c_ = cf[i];
#pragma unroll
            for (int c = 0; c < 4; ++c) {
                const int col = c * 16 + l16;
                atomicAdd(out_re  + dofs + col, acc1[c][i] * c_);
                atomicAdd(out_rst + dofs + col, (f2[so + col] + acc2[c][i]) * c_);
                atomicAdd(out_id  + dofs + col, f3[so + col] * c_);
            }
        }
    }
}

extern "C" void kernel_launch(void* const* d_in, const int* in_sizes, int n_in,
                              void* d_out, int out_size, void* d_ws, size_t ws_size,
                              hipStream_t stream) {
    const int*   src    = (const int*)d_in[0];
    const int*   dst    = (const int*)d_in[1];
    const float* review = (const float*)d_in[2];
    const float* ci     = (const float*)d_in[3];
    // d_in[4] = feature (unused by the reference computation)
    const float* W1     = (const float*)d_in[5];
    const float* W2     = (const float*)d_in[6];
    const float* f2     = (const float*)d_in[7];
    const float* f3     = (const float*)d_in[8];
    float* out = (float*)d_out;
    float* out_rst = out;
    float* out_re  = out + (size_t)NN * DD;
    float* out_id  = out + 2 * (size_t)NN * DD;

    // counts | offs | cursor | csum | cofs | epack(int4) | ftc(bf16 NN*128)
    const size_t NEED = sizeof(int) * ((size_t)3 * NN + 512) +
                        sizeof(int4) * (size_t)NE +
                        sizeof(__bf16) * (size_t)NN * 128;
    if (ws_size < NEED) {
        (void)hipMemsetAsync(out, 0, (size_t)out_size * sizeof(float), stream);
        gcn_mfma_kernel<<<2048, 256, 0, stream>>>(src, dst, review, ci, W1, W2, f2, f3, out);
        return;
    }

    char* w = (char*)d_ws;
    int* counts = (int*)w;    w += (size_t)NN * 4;
    int* offs   = (int*)w;    w += (size_t)NN * 4;
    int* cursor = (int*)w;    w += (size_t)NN * 4;
    int* csum   = (int*)w;    w += 256 * 4;
    int* cofs   = (int*)w;    w += 256 * 4;
    int4* epack = (int4*)w;   w += (size_t)NE * 16;
    __bf16* ftc = (__bf16*)w;

    k_zero       <<<(NN / 4 + 255) / 256, 256, 0, stream>>>(counts);
    k_prep       <<<3072, 256, 0, stream>>>(dst, f2, f3, ci, counts, ftc);
    k_chunk_sums <<<NCHUNK, 256, 0, stream>>>(counts, csum);
    k_scan_chunks<<<1, 64, 0, stream>>>(csum, cofs);
    k_chunk_scan <<<NCHUNK, 256, 0, stream>>>(counts, cofs, offs, cursor);
    k_permfill   <<<1024, 256, 0, stream>>>(dst, src, ci, cursor, epack);
    k_pull_fused <<<NN / 16, 256, 0, stream>>>(epack, offs, counts, review, ci, ftc,
                                               W1, W2, out_rst, out_re, out_id);
}

// Round 14
// 310.205 us; speedup vs baseline: 1.3668x; 1.3668x over previous
//
#include <hip/hip_runtime.h>

#define NN 200000
#define NE 1000000
#define DD 64
#define NCHUNK 196   // ceil(NN / 1024)

typedef __bf16 bf16x4 __attribute__((ext_vector_type(4)));
typedef __bf16 bf16x8 __attribute__((ext_vector_type(8)));
typedef float  f32x4  __attribute__((ext_vector_type(4)));
typedef int    i32x4  __attribute__((ext_vector_type(4)));

static __device__ __forceinline__ bf16x8 pack8(const float* __restrict__ p) {
    float4 a = *reinterpret_cast<const float4*>(p);
    float4 b = *reinterpret_cast<const float4*>(p + 4);
    bf16x8 r;
    r[0] = (__bf16)a.x; r[1] = (__bf16)a.y; r[2] = (__bf16)a.z; r[3] = (__bf16)a.w;
    r[4] = (__bf16)b.x; r[5] = (__bf16)b.y; r[6] = (__bf16)b.z; r[7] = (__bf16)b.w;
    return r;
}

// ---------- counts zero ----------
__global__ __launch_bounds__(256) void k_zero(int* __restrict__ counts) {
    const int i = (blockIdx.x * 256 + threadIdx.x) * 4;
    if (i + 3 < NN) *reinterpret_cast<int4*>(counts + i) = make_int4(0, 0, 0, 0);
    else for (int j = i; j < NN; ++j) counts[j] = 0;
}

// ---------- Prep: histogram (blocks 0..1023) || interleaved ci-folded table ----------
// ftc[s][t*8+0..3] = bf16(f2[s][t*4..]*ci[s]); ftc[s][t*8+4..7] = bf16(f3[..]*ci[s])
__global__ __launch_bounds__(256) void k_prep(
    const int* __restrict__ dst, const float* __restrict__ f2,
    const float* __restrict__ f3, const float* __restrict__ ci,
    int* __restrict__ counts, __bf16* __restrict__ ftc)
{
    const int b = blockIdx.x;
    if (b < 1024) {
        for (int e = b * 256 + threadIdx.x; e < NE; e += 1024 * 256)
            atomicAdd(&counts[dst[e]], 1);
    } else {
        const int nconv = (gridDim.x - 1024) * 256;
        const int total = NN * 16;                    // 16B output chunks
        for (int cch = (b - 1024) * 256 + threadIdx.x; cch < total; cch += nconv) {
            const int row = cch >> 4;
            const int t   = cch & 15;
            const float c = ci[row];
            const float4 a = *reinterpret_cast<const float4*>(f2 + (size_t)row * DD + t * 4);
            const float4 v = *reinterpret_cast<const float4*>(f3 + (size_t)row * DD + t * 4);
            bf16x8 o;
            o[0] = (__bf16)(a.x * c); o[1] = (__bf16)(a.y * c);
            o[2] = (__bf16)(a.z * c); o[3] = (__bf16)(a.w * c);
            o[4] = (__bf16)(v.x * c); o[5] = (__bf16)(v.y * c);
            o[6] = (__bf16)(v.z * c); o[7] = (__bf16)(v.w * c);
            *reinterpret_cast<bf16x8*>(ftc + (size_t)row * 128 + t * 8) = o;
        }
    }
}

// ---------- CSR scan ----------
__global__ __launch_bounds__(256) void k_chunk_sums(const int* __restrict__ counts,
                                                    int* __restrict__ csum) {
    const int b = blockIdx.x, tid = threadIdx.x;
    const int base = b * 1024 + tid * 4;
    int s = 0;
#pragma unroll
    for (int j = 0; j < 4; ++j) {
        const int i = base + j;
        if (i < NN) s += counts[i];
    }
#pragma unroll
    for (int d = 32; d > 0; d >>= 1) s += __shfl_down(s, d);
    __shared__ int wsum[4];
    if ((tid & 63) == 0) wsum[tid >> 6] = s;
    __syncthreads();
    if (tid == 0) csum[b] = wsum[0] + wsum[1] + wsum[2] + wsum[3];
}

__global__ void k_scan_chunks(const int* __restrict__ csum, int* __restrict__ cofs) {
    if (threadIdx.x == 0 && blockIdx.x == 0) {
        int acc = 0;
        for (int i = 0; i < NCHUNK; ++i) { cofs[i] = acc; acc += csum[i]; }
    }
}

__global__ __launch_bounds__(256) void k_chunk_scan(const int* __restrict__ counts,
                                                    const int* __restrict__ cofs,
                                                    int* __restrict__ offs,
                                                    int* __restrict__ cursor) {
    const int b = blockIdx.x, tid = threadIdx.x;
    const int lane = tid & 63, wv = tid >> 6;
    const int base = b * 1024 + tid * 4;
    int c[4];
#pragma unroll
    for (int j = 0; j < 4; ++j) {
        const int i = base + j;
        c[j] = (i < NN) ? counts[i] : 0;
    }
    const int ls = c[0] + c[1] + c[2] + c[3];
    int v = ls;
#pragma unroll
    for (int d = 1; d < 64; d <<= 1) {
        const int u = __shfl_up(v, d);
        if (lane >= d) v += u;
    }
    __shared__ int wsum[4];
    if (lane == 63) wsum[wv] = v;
    __syncthreads();
    int wbase = 0;
    for (int w = 0; w < wv; ++w) wbase += wsum[w];
    int excl = cofs[b] + wbase + (v - ls);
#pragma unroll
    for (int j = 0; j < 4; ++j) {
        const int i = base + j;
        if (i < NN) { offs[i] = excl; cursor[i] = excl; }
        excl += c[j];
    }
}

// Fill CSR slots: epack[pos] = {edge, src, bits(ci[src]), 0} — one 16B write.
__global__ __launch_bounds__(256) void k_permfill(const int* __restrict__ dst,
                                                  const int* __restrict__ src,
                                                  const float* __restrict__ ci,
                                                  int* __restrict__ cursor,
                                                  int4* __restrict__ epack) {
    for (int e = blockIdx.x * blockDim.x + threadIdx.x; e < NE;
         e += gridDim.x * blockDim.x) {
        const int s = src[e];
        const float cs = ci[s];
        const int pos = atomicAdd(&cursor[dst[e]], 1);
        epack[pos] = make_int4(e, s, __float_as_int(cs), 0);
    }
}

// ---------- Fused pull + node-GEMM ----------
// Block = 256 threads = 16 quarters = 16 nodes = one MFMA A-tile.
// Unroll-4 with STATIC indices everywhere (rule #20: runtime-indexed
// ext_vector arrays spill to scratch — R13's 73% VALUBusy regression).
__global__ __launch_bounds__(256) void k_pull_fused(
    const int4* __restrict__ epack, const int* __restrict__ offs,
    const int* __restrict__ counts, const float* __restrict__ review,
    const float* __restrict__ ci, const __bf16* __restrict__ ftc,
    const float* __restrict__ W1, const float* __restrict__ W2,
    float* __restrict__ out_rst, float* __restrict__ out_re,
    float* __restrict__ out_id)
{
    __shared__ __bf16 At[16][72];   // bf16(cid*hx); padded row (144B) vs bank conflicts
    __shared__ float  S2[16][68];   // cid*sum(f2c); padded row (272B)

    const int tid = threadIdx.x;
    const int l16 = tid & 15;
    const int q   = tid >> 4;               // node-in-block
    const int n   = blockIdx.x * 16 + q;

    const int beg = offs[n];
    const int cnt = counts[n];

    f32x4 ax0 = {0,0,0,0}, ax1 = {0,0,0,0}, ax2 = {0,0,0,0}, ax3 = {0,0,0,0};
    f32x4 a20 = {0,0,0,0}, a21 = {0,0,0,0}, a22 = {0,0,0,0}, a23 = {0,0,0,0};
    f32x4 a30 = {0,0,0,0}, a31 = {0,0,0,0}, a32 = {0,0,0,0}, a33 = {0,0,0,0};

#define EDGE_ACC(AX, A2, A3, EP)                                               \
    {                                                                          \
        const f32x4 r = __builtin_nontemporal_load(                            \
            reinterpret_cast<const f32x4*>(review + (size_t)(EP)[0] * DD + l16 * 4)); \
        const bf16x8 t = *reinterpret_cast<const bf16x8*>(                     \
            ftc + (size_t)(EP)[1] * 128 + l16 * 8);                            \
        const float cs = __int_as_float((EP)[2]);                              \
        AX[0] = fmaf(r[0], cs, AX[0]); AX[1] = fmaf(r[1], cs, AX[1]);          \
        AX[2] = fmaf(r[2], cs, AX[2]); AX[3] = fmaf(r[3], cs, AX[3]);          \
        A2[0] += (float)t[0]; A2[1] += (float)t[1];                            \
        A2[2] += (float)t[2]; A2[3] += (float)t[3];                            \
        A3[0] += (float)t[4]; A3[1] += (float)t[5];                            \
        A3[2] += (float)t[6]; A3[3] += (float)t[7];                            \
    }

    int k = 0;
    for (; k + 4 <= cnt; k += 4) {
        const i32x4 e0 = __builtin_nontemporal_load(
            reinterpret_cast<const i32x4*>(epack + (size_t)(beg + k + 0)));
        const i32x4 e1 = __builtin_nontemporal_load(
            reinterpret_cast<const i32x4*>(epack + (size_t)(beg + k + 1)));
        const i32x4 e2 = __builtin_nontemporal_load(
            reinterpret_cast<const i32x4*>(epack + (size_t)(beg + k + 2)));
        const i32x4 e3 = __builtin_nontemporal_load(
            reinterpret_cast<const i32x4*>(epack + (size_t)(beg + k + 3)));
        EDGE_ACC(ax0, a20, a30, e0)
        EDGE_ACC(ax1, a21, a31, e1)
        EDGE_ACC(ax2, a22, a32, e2)
        EDGE_ACC(ax3, a23, a33, e3)
    }
    // Remainder: static chain indices only (0..2 leftover edges -> chains 0..2).
    if (k < cnt) {
        const i32x4 e0 = __builtin_nontemporal_load(
            reinterpret_cast<const i32x4*>(epack + (size_t)(beg + k)));
        EDGE_ACC(ax0, a20, a30, e0)
        ++k;
    }
    if (k < cnt) {
        const i32x4 e1 = __builtin_nontemporal_load(
            reinterpret_cast<const i32x4*>(epack + (size_t)(beg + k)));
        EDGE_ACC(ax1, a21, a31, e1)
        ++k;
    }
    if (k < cnt) {
        const i32x4 e2 = __builtin_nontemporal_load(
            reinterpret_cast<const i32x4*>(epack + (size_t)(beg + k)));
        EDGE_ACC(ax2, a22, a32, e2)
        ++k;
    }
#undef EDGE_ACC

    const float cid = ci[n];
    f32x4 axs = {ax0[0]+ax1[0]+ax2[0]+ax3[0], ax0[1]+ax1[1]+ax2[1]+ax3[1],
                 ax0[2]+ax1[2]+ax2[2]+ax3[2], ax0[3]+ax1[3]+ax2[3]+ax3[3]};
    f32x4 a2s = {a20[0]+a21[0]+a22[0]+a23[0], a20[1]+a21[1]+a22[1]+a23[1],
                 a20[2]+a21[2]+a22[2]+a23[2], a20[3]+a21[3]+a22[3]+a23[3]};
    f32x4 a3s = {a30[0]+a31[0]+a32[0]+a33[0], a30[1]+a31[1]+a32[1]+a33[1],
                 a30[2]+a31[2]+a32[2]+a33[2], a30[3]+a31[3]+a32[3]+a33[3]};

    // out_id final (streaming).
    f32x4 v3 = {a3s[0] * cid, a3s[1] * cid, a3s[2] * cid, a3s[3] * cid};
    __builtin_nontemporal_store(v3, reinterpret_cast<f32x4*>(out_id + (size_t)n * DD + l16 * 4));

    // Stage GEMM input tiles.
    bf16x4 hb;
    hb[0] = (__bf16)(axs[0] * cid); hb[1] = (__bf16)(axs[1] * cid);
    hb[2] = (__bf16)(axs[2] * cid); hb[3] = (__bf16)(axs[3] * cid);
    *reinterpret_cast<bf16x4*>(&At[q][l16 * 4]) = hb;
    f32x4 s2v = {a2s[0] * cid, a2s[1] * cid, a2s[2] * cid, a2s[3] * cid};
    *reinterpret_cast<f32x4*>(&S2[q][l16 * 4]) = s2v;
    __syncthreads();

    // GEMM: wave w computes col-block w for both W1 (out_re) and W2 (out_rst).
    const int w  = tid >> 6;          // 0..3
    const int lq = (tid & 63) >> 4;   // 0..3
    bf16x8 w1f[2], w2f[2];
#pragma unroll
    for (int kk = 0; kk < 2; ++kk) {
        const int off = (w * 16 + l16) * DD + kk * 32 + lq * 8;
        w1f[kk] = pack8(W1 + off);
        w2f[kk] = pack8(W2 + off);
    }
    const bf16x8 a0 = *reinterpret_cast<const bf16x8*>(&At[l16][lq * 8]);
    const bf16x8 a1 = *reinterpret_cast<const bf16x8*>(&At[l16][lq * 8 + 32]);

    const f32x4 zero = {0.f, 0.f, 0.f, 0.f};
    f32x4 acc1 = zero, acc2 = zero;
    acc1 = __builtin_amdgcn_mfma_f32_16x16x32_bf16(a0, w1f[0], acc1, 0, 0, 0);
    acc1 = __builtin_amdgcn_mfma_f32_16x16x32_bf16(a1, w1f[1], acc1, 0, 0, 0);
    acc2 = __builtin_amdgcn_mfma_f32_16x16x32_bf16(a0, w2f[0], acc2, 0, 0, 0);
    acc2 = __builtin_amdgcn_mfma_f32_16x16x32_bf16(a1, w2f[1], acc2, 0, 0, 0);

    const int base = blockIdx.x * 16;
#pragma unroll
    for (int i = 0; i < 4; ++i) {
        const int row = lq * 4 + i;
        const size_t o = (size_t)(base + row) * DD + w * 16 + l16;
        __builtin_nontemporal_store(acc1[i], out_re + o);
        __builtin_nontemporal_store(acc2[i] + S2[row][w * 16 + l16], out_rst + o);
    }
}

// ---------- Fallback (round-2 proven kernel) if ws too small ----------
__global__ __launch_bounds__(256) void gcn_mfma_kernel(
    const int* __restrict__ src, const int* __restrict__ dst,
    const float* __restrict__ review, const float* __restrict__ ci,
    const float* __restrict__ W1, const float* __restrict__ W2,
    const float* __restrict__ f2, const float* __restrict__ f3,
    float* __restrict__ out)
{
    float* out_rst = out;
    float* out_re  = out + (size_t)NN * DD;
    float* out_id  = out + 2 * (size_t)NN * DD;
    const int lane = threadIdx.x & 63;
    const int l16  = lane & 15;
    const int lq   = lane >> 4;
    const int wid  = blockIdx.x * (blockDim.x >> 6) + (threadIdx.x >> 6);
    const int nw   = gridDim.x * (blockDim.x >> 6);

    bf16x8 w1f[4][2], w2f[4][2];
#pragma unroll
    for (int c = 0; c < 4; ++c)
#pragma unroll
        for (int kk = 0; kk < 2; ++kk) {
            const int off = (c * 16 + l16) * DD + kk * 32 + lq * 8;
            w1f[c][kk] = pack8(W1 + off);
            w2f[c][kk] = pack8(W2 + off);
        }
    const f32x4 zero = {0.f, 0.f, 0.f, 0.f};
    for (int t = wid; t < NE / 16; t += nw) {
        const int e0 = t * 16;
        const float* xr = review + (size_t)(e0 + l16) * DD + lq * 8;
        const bf16x8 a0 = pack8(xr);
        const bf16x8 a1 = pack8(xr + 32);
        f32x4 acc1[4], acc2[4];
#pragma unroll
        for (int c = 0; c < 4; ++c) { acc1[c] = zero; acc2[c] = zero; }
#pragma unroll
        for (int c = 0; c < 4; ++c) {
            acc1[c] = __builtin_amdgcn_mfma_f32_16x16x32_bf16(a0, w1f[c][0], acc1[c], 0, 0, 0);
            acc1[c] = __builtin_amdgcn_mfma_f32_16x16x32_bf16(a1, w1f[c][1], acc1[c], 0, 0, 0);
            acc2[c] = __builtin_amdgcn_mfma_f32_16x16x32_bf16(a0, w2f[c][0], acc2[c], 0, 0, 0);
            acc2[c] = __builtin_amdgcn_mfma_f32_16x16x32_bf16(a1, w2f[c][1], acc2[c], 0, 0, 0);
        }
        int sA[4], dA[4]; float cf[4];
#pragma unroll
        for (int i = 0; i < 4; ++i) {
            const int e = e0 + lq * 4 + i;
            sA[i] = src[e]; dA[i] = dst[e];
            cf[i] = ci[sA[i]] * ci[dA[i]];
        }
#pragma unroll
        for (int i = 0; i < 4; ++i) {
            const size_t so = (size_t)sA[i] * DD;
            const size_t dofs = (size_t)dA[i] * DD;
            const float c_ = cf[i];
#pragma unroll
            for (int c = 0; c < 4; ++c) {
                const int col = c * 16 + l16;
                atomicAdd(out_re  + dofs + col, acc1[c][i] * c_);
                atomicAdd(out_rst + dofs + col, (f2[so + col] + acc2[c][i]) * c_);
                atomicAdd(out_id  + dofs + col, f3[so + col] * c_);
            }
        }
    }
}

extern "C" void kernel_launch(void* const* d_in, const int* in_sizes, int n_in,
                              void* d_out, int out_size, void* d_ws, size_t ws_size,
                              hipStream_t stream) {
    const int*   src    = (const int*)d_in[0];
    const int*   dst    = (const int*)d_in[1];
    const float* review = (const float*)d_in[2];
    const float* ci     = (const float*)d_in[3];
    // d_in[4] = feature (unused by the reference computation)
    const float* W1     = (const float*)d_in[5];
    const float* W2     = (const float*)d_in[6];
    const float* f2     = (const float*)d_in[7];
    const float* f3     = (const float*)d_in[8];
    float* out = (float*)d_out;
    float* out_rst = out;
    float* out_re  = out + (size_t)NN * DD;
    float* out_id  = out + 2 * (size_t)NN * DD;

    // counts | offs | cursor | csum | cofs | epack(int4) | ftc(bf16 NN*128)
    const size_t NEED = sizeof(int) * ((size_t)3 * NN + 512) +
                        sizeof(int4) * (size_t)NE +
                        sizeof(__bf16) * (size_t)NN * 128;
    if (ws_size < NEED) {
        (void)hipMemsetAsync(out, 0, (size_t)out_size * sizeof(float), stream);
        gcn_mfma_kernel<<<2048, 256, 0, stream>>>(src, dst, review, ci, W1, W2, f2, f3, out);
        return;
    }

    char* w = (char*)d_ws;
    int* counts = (int*)w;    w += (size_t)NN * 4;
    int* offs   = (int*)w;    w += (size_t)NN * 4;
    int* cursor = (int*)w;    w += (size_t)NN * 4;
    int* csum   = (int*)w;    w += 256 * 4;
    int* cofs   = (int*)w;    w += 256 * 4;
    int4* epack = (int4*)w;   w += (size_t)NE * 16;
    __bf16* ftc = (__bf16*)w;

    k_zero       <<<(NN / 4 + 255) / 256, 256, 0, stream>>>(counts);
    k_prep       <<<3072, 256, 0, stream>>>(dst, f2, f3, ci, counts, ftc);
    k_chunk_sums <<<NCHUNK, 256, 0, stream>>>(counts, csum);
    k_scan_chunks<<<1, 64, 0, stream>>>(csum, cofs);
    k_chunk_scan <<<NCHUNK, 256, 0, stream>>>(counts, cofs, offs, cursor);
    k_permfill   <<<1024, 256, 0, stream>>>(dst, src, ci, cursor, epack);
    k_pull_fused <<<NN / 16, 256, 0, stream>>>(epack, offs, counts, review, ci, ftc,
                                               W1, W2, out_rst, out_re, out_id);
}